// Round 5
// baseline (213.609 us; speedup 1.0000x reference)
//
#include <hip/hip_runtime.h>
#include <hip/hip_bf16.h>

typedef unsigned int u32;
typedef unsigned long long u64;
typedef unsigned short u16;

#define NPOS 16384      // B*H*W
#define DCH  128
#define KCB  8192
#define HW   1024
#define BETA 0.25f
#define ZQ_SZ 2097152
#define MARGIN 0.022f   // >= 2*delta_bf16 (0.0157) + headroom
#define QCAP 2048
#define ZSTR 132        // LDS row stride in floats
#define ROWS 32         // rows per block

typedef __attribute__((ext_vector_type(8))) short short8;
typedef __attribute__((ext_vector_type(4))) float f32x4;

__device__ inline u16 f2bf(float x) {   // RNE float->bf16
    u32 u = __float_as_uint(x);
    return (u16)((u + 0x7FFFu + ((u >> 16) & 1u)) >> 16);
}
__device__ inline u32 mono(float f) {   // monotone float->u32
    u32 b = __float_as_uint(f);
    return (b & 0x80000000u) ? ~b : (b | 0x80000000u);
}

// ---------------- codebook prep: bf16 convert + squared norms ----------------
__global__ __launch_bounds__(256) void kwprep(const float* __restrict__ w,
                                              u16* __restrict__ wb,
                                              float* __restrict__ csq) {
    const int t = threadIdx.x;
    const int row = blockIdx.x * 16 + (t >> 4);
    const int l = t & 15;
    const float4* src = (const float4*)(w + (size_t)row * DCH + l * 8);
    float4 a = src[0], b = src[1];
    float s = a.x*a.x + a.y*a.y + a.z*a.z + a.w*a.w
            + b.x*b.x + b.y*b.y + b.z*b.z + b.w*b.w;
    union { u16 h[8]; uint4 v; } u;
    u.h[0]=f2bf(a.x); u.h[1]=f2bf(a.y); u.h[2]=f2bf(a.z); u.h[3]=f2bf(a.w);
    u.h[4]=f2bf(b.x); u.h[5]=f2bf(b.y); u.h[6]=f2bf(b.z); u.h[7]=f2bf(b.w);
    *(uint4*)(wb + (size_t)row * DCH + l * 8) = u.v;
    s += __shfl_xor(s, 1, 64);
    s += __shfl_xor(s, 2, 64);
    s += __shfl_xor(s, 4, 64);
    s += __shfl_xor(s, 8, 64);
    if (l == 0) csq[row] = s;
}

// ---- fused main: 512 thr / 32 rows / full-codebook barrier-free sweep ----
__global__ __launch_bounds__(512, 4) void kmain(const float* __restrict__ z,
                                                const float* __restrict__ wgt,
                                                const u16* __restrict__ wb,
                                                const float* __restrict__ csq,
                                                float* __restrict__ out) {
    __shared__ __align__(16) float ztl[ROWS * ZSTR];   // 16.9 KB normalized rows (fp32)
    __shared__ __align__(16) u32 pool[ROWS * ZSTR];    // 16.9 KB: queue, then Wg
    __shared__ u32 rowMinU[ROWS];
    __shared__ u64 finalkey[ROWS];
    __shared__ float psum[ROWS][16];
    __shared__ float invL[ROWS];
    __shared__ int codes[ROWS];
    __shared__ float lsum[8];
    __shared__ int qcnt;

    const int t = threadIdx.x;                 // 0..511
    const int lane = t & 63;
    const int w = t >> 6;                      // wave 0..7: owns codes w*16..w*16+15 per tile
    const int n0 = blockIdx.x * ROWS;
    const int b = n0 >> 10, hw0 = n0 & 1023;
    const int p = t & 31, g = t >> 5;          // position / channel-group for IO phases

    // ---- phase 0: load + l2-normalize 32 rows into LDS ----
    float vch[8];
    {
        const float* zp = z + (size_t)b * DCH * HW + hw0 + p;
        #pragma unroll
        for (int j = 0; j < 8; ++j)
            vch[j] = zp[(size_t)(g + j * 16) * HW];
        float s = 0.f;
        #pragma unroll
        for (int j = 0; j < 8; ++j) s += vch[j] * vch[j];
        psum[p][g] = s;
    }
    if (t < ROWS) { rowMinU[t] = 0x7f800000u; finalkey[t] = ~0ULL; }
    if (t == 0) qcnt = 0;
    __syncthreads();
    if (t < ROWS) {
        float ss = 0.f;
        #pragma unroll
        for (int j = 0; j < 16; ++j) ss += psum[t][j];
        invL[t] = 1.0f / fmaxf(sqrtf(ss), 1e-12f);
    }
    __syncthreads();
    {
        float inv = invL[p];
        #pragma unroll
        for (int j = 0; j < 8; ++j)
            ztl[p * ZSTR + g + j * 16] = vch[j] * inv;
    }
    __syncthreads();

    // ---- A fragments (bf16): row = lane&15, k = (lane>>4)*8 + j ----
    short8 af[2][4];
    #pragma unroll
    for (int rt = 0; rt < 2; ++rt)
        #pragma unroll
        for (int ks = 0; ks < 4; ++ks) {
            int row = rt * 16 + (lane & 15);
            int kb = ks * 32 + (lane >> 4) * 8;
            const float4* zr = (const float4*)&ztl[row * ZSTR + kb];
            float4 x0 = zr[0], x1 = zr[1];
            union { u16 h[8]; short8 v; } uu;
            uu.h[0]=f2bf(x0.x); uu.h[1]=f2bf(x0.y); uu.h[2]=f2bf(x0.z); uu.h[3]=f2bf(x0.w);
            uu.h[4]=f2bf(x1.x); uu.h[5]=f2bf(x1.y); uu.h[6]=f2bf(x1.z); uu.h[7]=f2bf(x1.w);
            af[rt][ks] = uu.v;
        }

    // per-thread B base: code = kt*128 + w*16 + (lane&15), k-chunk = (lane>>4)*8
    const u16* wtb = wb + ((w * 16 + (lane & 15)) << 7) + ((lane >> 4) << 3);

    float bmin[8], thr[8];
    #pragma unroll
    for (int i = 0; i < 8; ++i) { bmin[i] = 3.4e38f; thr[i] = -1.f; }

    short8 bA[4], bB[4];

#define LOADB(D, KT) do { \
    const u16* bsrc = wtb + (size_t)(KT) * 16384; \
    _Pragma("unroll") \
    for (int ks_ = 0; ks_ < 4; ++ks_) \
        D[ks_] = *(const short8*)(bsrc + ks_ * 32); \
} while (0)

#define COMPUTE(S, KT, COLLECT) do { \
    f32x4 acc[2] = {}; \
    _Pragma("unroll") \
    for (int ks_ = 0; ks_ < 4; ++ks_) { \
        acc[0] = __builtin_amdgcn_mfma_f32_16x16x32_bf16(af[0][ks_], S[ks_], acc[0], 0, 0, 0); \
        acc[1] = __builtin_amdgcn_mfma_f32_16x16x32_bf16(af[1][ks_], S[ks_], acc[1], 0, 0, 0); \
    } \
    _Pragma("unroll") \
    for (int rt_ = 0; rt_ < 2; ++rt_) \
        _Pragma("unroll") \
        for (int e_ = 0; e_ < 4; ++e_) { \
            float d_ = fmaf(acc[rt_][e_], -2.f, 2.125f); \
            int i_ = rt_ * 4 + e_; \
            bmin[i_] = fminf(bmin[i_], d_); \
            if (COLLECT && d_ <= thr[i_]) { \
                u32 rl_ = (u32)(rt_ * 16 + (lane >> 4) * 4 + e_); \
                u32 cb_ = (u32)((KT) * 128 + w * 16 + (lane & 15)); \
                int qi_ = atomicAdd(&qcnt, 1); \
                if (qi_ < QCAP) pool[qi_] = (rl_ << 13) | cb_; \
            } \
        } \
} while (0)

#define REFRESH() do { \
    _Pragma("unroll") \
    for (int i_ = 0; i_ < 8; ++i_) { \
        float v_ = bmin[i_]; \
        v_ = fminf(v_, __shfl_xor(v_, 1, 64)); \
        v_ = fminf(v_, __shfl_xor(v_, 2, 64)); \
        v_ = fminf(v_, __shfl_xor(v_, 4, 64)); \
        v_ = fminf(v_, __shfl_xor(v_, 8, 64)); \
        if ((lane & 15) == 0) \
            atomicMin(&rowMinU[(i_ >> 2) * 16 + (lane >> 4) * 4 + (i_ & 3)], __float_as_uint(v_)); \
    } \
    _Pragma("unroll") \
    for (int i_ = 0; i_ < 8; ++i_) \
        thr[i_] = fminf(__uint_as_float(rowMinU[(i_ >> 2) * 16 + (lane >> 4) * 4 + (i_ & 3)]), bmin[i_]) + MARGIN; \
} while (0)

    // prologue: evaluate tile 0 (no collection) to seed thresholds
    LOADB(bA, 0);
    COMPUTE(bA, 0, false);
    REFRESH();

    // barrier-free sweep: 64 k-tiles, depth-1 register prefetch
    #pragma unroll 1
    for (int kt2 = 0; kt2 < 32; ++kt2) {
        const int kt0 = kt2 * 2;
        LOADB(bB, kt0 + 1);
        COMPUTE(bA, kt0, true);
        LOADB(bA, (kt0 + 2) & 63);
        COMPUTE(bB, kt0 + 1, true);
        if ((kt2 & 3) == 3) REFRESH();   // every 8 k-tiles
    }

    __syncthreads();

    // ---- exact fp32 repair: one candidate per 16-lane group (32 groups) ----
    {
        int nq = qcnt < QCAP ? qcnt : QCAP;
        int gq = t >> 4, l = t & 15;
        for (int qi = gq; qi < nq; qi += 32) {
            u32 e = pool[qi];
            int rl = e >> 13;
            int code = e & 0x1FFF;
            const float4* zr = (const float4*)&ztl[rl * ZSTR + l * 8];
            const float4* wr = (const float4*)(wgt + (size_t)code * DCH + l * 8);
            float4 za = zr[0], zb = zr[1], wa = wr[0], wbv = wr[1];
            float s = 0.f;
            s = fmaf(za.x, wa.x, s); s = fmaf(za.y, wa.y, s);
            s = fmaf(za.z, wa.z, s); s = fmaf(za.w, wa.w, s);
            s = fmaf(zb.x, wbv.x, s); s = fmaf(zb.y, wbv.y, s);
            s = fmaf(zb.z, wbv.z, s); s = fmaf(zb.w, wbv.w, s);
            s += __shfl_xor(s, 1, 64);
            s += __shfl_xor(s, 2, 64);
            s += __shfl_xor(s, 4, 64);
            s += __shfl_xor(s, 8, 64);
            if (l == 0) {
                float ed = csq[code] - 2.0f * s;
                u64 key = ((u64)mono(ed) << 32) | (u32)code;
                atomicMin((unsigned long long*)&finalkey[rl], (unsigned long long)key);
            }
        }
    }
    __syncthreads();

    // ---- finalize: indices, gather (reuse pool as Wg), straight-through, loss ----
    if (t < ROWS) {
        u32 code = (u32)finalkey[t];
        codes[t] = (int)code;
        out[ZQ_SZ + 1 + n0 + t] = (float)code;
    }
    __syncthreads();
    float* Wg = (float*)pool;            // [32][ZSTR] fp32
    {
        int r = t >> 4, ch = t & 15;
        const float4* wr = (const float4*)(wgt + (size_t)codes[r] * DCH + ch * 8);
        float4* dst = (float4*)&Wg[r * ZSTR + ch * 8];
        dst[0] = wr[0];
        dst[1] = wr[1];
    }
    __syncthreads();
    {
        float* ob = out + (size_t)b * DCH * HW + hw0;
        float sq = 0.f;
        #pragma unroll
        for (int j = 0; j < 8; ++j) {
            int c = g + j * 16;
            float zv = ztl[p * ZSTR + c];
            float diff = Wg[p * ZSTR + c] - zv;
            ob[(size_t)c * HW + p] = zv + diff;   // straight-through forward value
            sq += diff * diff;
        }
        #pragma unroll
        for (int o = 32; o > 0; o >>= 1) sq += __shfl_down(sq, o, 64);
        if (lane == 0) lsum[w] = sq;
    }
    __syncthreads();
    if (t == 0) {
        float s = lsum[0] + lsum[1] + lsum[2] + lsum[3]
                + lsum[4] + lsum[5] + lsum[6] + lsum[7];
        atomicAdd(out + ZQ_SZ, s * (BETA / (float)ZQ_SZ));
    }

#undef LOADB
#undef COMPUTE
#undef REFRESH
}

extern "C" void kernel_launch(void* const* d_in, const int* in_sizes, int n_in,
                              void* d_out, int out_size, void* d_ws, size_t ws_size,
                              hipStream_t stream) {
    const float* z = (const float*)d_in[0];
    const float* w = (const float*)d_in[1];
    float* out = (float*)d_out;
    float* wsf = (float*)d_ws;

    // ws layout: wb u16[1048576] (= 524288 floats) | csq f32[8192]
    u16* wb = (u16*)wsf;
    float* csq = wsf + 524288;

    kwprep<<<512, 256, 0, stream>>>(w, wb, csq);
    hipMemsetAsync(out + ZQ_SZ, 0, 4, stream);      // zero the loss slot
    kmain<<<512, 512, 0, stream>>>(z, w, wb, csq, out);
}

// Round 6
// 212.706 us; speedup vs baseline: 1.0042x; 1.0042x over previous
//
#include <hip/hip_runtime.h>
#include <hip/hip_bf16.h>

typedef unsigned int u32;
typedef unsigned long long u64;
typedef unsigned short u16;

#define NPOS 16384      // B*H*W
#define DCH  128
#define KCB  8192
#define HW   1024
#define BETA 0.25f
#define ZQ_SZ 2097152
#define MARGIN 0.022f   // >= 2*delta_bf16 (0.0157) + headroom
#define QCAP 3072
#define ZSTR 132        // ztl LDS row stride in floats
#define ROWS 64         // rows per block

typedef __attribute__((ext_vector_type(8))) short short8;
typedef __attribute__((ext_vector_type(4))) float f32x4;

#define GLOAD16(G, L) __builtin_amdgcn_global_load_lds( \
    (const __attribute__((address_space(1))) u32*)(const void*)(G), \
    (__attribute__((address_space(3))) u32*)(void*)(L), 16, 0, 0)

__device__ inline u16 f2bf(float x) {   // RNE float->bf16
    u32 u = __float_as_uint(x);
    return (u16)((u + 0x7FFFu + ((u >> 16) & 1u)) >> 16);
}
__device__ inline u32 mono(float f) {   // monotone float->u32
    u32 b = __float_as_uint(f);
    return (b & 0x80000000u) ? ~b : (b | 0x80000000u);
}

// ---------------- codebook prep: bf16 convert + squared norms ----------------
__global__ __launch_bounds__(256) void kwprep(const float* __restrict__ w,
                                              u16* __restrict__ wb,
                                              float* __restrict__ csq) {
    const int t = threadIdx.x;
    const int row = blockIdx.x * 16 + (t >> 4);
    const int l = t & 15;
    const float4* src = (const float4*)(w + (size_t)row * DCH + l * 8);
    float4 a = src[0], b = src[1];
    float s = a.x*a.x + a.y*a.y + a.z*a.z + a.w*a.w
            + b.x*b.x + b.y*b.y + b.z*b.z + b.w*b.w;
    union { u16 h[8]; uint4 v; } u;
    u.h[0]=f2bf(a.x); u.h[1]=f2bf(a.y); u.h[2]=f2bf(a.z); u.h[3]=f2bf(a.w);
    u.h[4]=f2bf(b.x); u.h[5]=f2bf(b.y); u.h[6]=f2bf(b.z); u.h[7]=f2bf(b.w);
    *(uint4*)(wb + (size_t)row * DCH + l * 8) = u.v;
    s += __shfl_xor(s, 1, 64);
    s += __shfl_xor(s, 2, 64);
    s += __shfl_xor(s, 4, 64);
    s += __shfl_xor(s, 8, 64);
    if (l == 0) csq[row] = s;
}

// ---- fused main: 512 thr / 64 rows / LDS-staged codebook sweep + repair + outputs ----
__global__ __launch_bounds__(512, 2) void kmain(const float* __restrict__ z,
                                                const float* __restrict__ wgt,
                                                const u16* __restrict__ wb,
                                                const float* __restrict__ csq,
                                                float* __restrict__ out) {
    __shared__ __align__(16) u16 Wb[2][128 * 128];     // 64 KB B double buffer (swizzled)
    __shared__ __align__(16) float ztl[ROWS * ZSTR];   // 33.8 KB fp32 normalized rows
    __shared__ u32 queue[QCAP];                        // 12 KB candidate queue
    __shared__ u32 rowMinU[ROWS];
    __shared__ u64 finalkey[ROWS];
    __shared__ float psum[ROWS][8];
    __shared__ float invL[ROWS];
    __shared__ int codes[ROWS];
    __shared__ float lsum[8];
    __shared__ int qcnt;

    const int t = threadIdx.x;                 // 0..511
    const int lane = t & 63;
    const int w = t >> 6;                      // wave 0..7
    const int wr = w >> 2, wc = w & 3;         // 2x4: rows wr*32+, codes wc*32+
    const int n0 = blockIdx.x * ROWS;
    const int b = n0 >> 10, hw0 = n0 & 1023;
    const int p = lane;                        // row slot for IO phases

    // ---- phase 0: load + l2-normalize 64 rows into LDS ----
    float vch[16];
    {
        const float* zp = z + (size_t)b * DCH * HW + hw0 + p;
        #pragma unroll
        for (int j = 0; j < 16; ++j)
            vch[j] = zp[(size_t)(w * 16 + j) * HW];
        float s = 0.f;
        #pragma unroll
        for (int j = 0; j < 16; ++j) s += vch[j] * vch[j];
        psum[p][w] = s;
    }
    if (t < ROWS) { rowMinU[t] = 0x7f800000u; finalkey[t] = ~0ULL; }
    if (t == 0) qcnt = 0;
    __syncthreads();
    if (t < ROWS) {
        float ss = 0.f;
        #pragma unroll
        for (int j = 0; j < 8; ++j) ss += psum[t][j];
        invL[t] = 1.0f / fmaxf(sqrtf(ss), 1e-12f);
    }
    __syncthreads();
    {
        float inv = invL[p];
        #pragma unroll
        for (int j = 0; j < 16; ++j)
            ztl[p * ZSTR + w * 16 + j] = vch[j] * inv;
    }
    __syncthreads();

    // ---- A fragments (bf16) in registers: row = lane&15, k = (lane>>4)*8 + j ----
    short8 af[2][4];
    #pragma unroll
    for (int mi = 0; mi < 2; ++mi)
        #pragma unroll
        for (int ks = 0; ks < 4; ++ks) {
            int row = wr * 32 + mi * 16 + (lane & 15);
            int kb = ks * 32 + (lane >> 4) * 8;
            const float4* zr = (const float4*)&ztl[row * ZSTR + kb];
            float4 x0 = zr[0], x1 = zr[1];
            union { u16 h[8]; short8 v; } uu;
            uu.h[0]=f2bf(x0.x); uu.h[1]=f2bf(x0.y); uu.h[2]=f2bf(x0.z); uu.h[3]=f2bf(x0.w);
            uu.h[4]=f2bf(x1.x); uu.h[5]=f2bf(x1.y); uu.h[6]=f2bf(x1.z); uu.h[7]=f2bf(x1.w);
            af[mi][ks] = uu.v;
        }

    float bmin[8], thr[8];
    #pragma unroll
    for (int i = 0; i < 8; ++i) { bmin[i] = 3.4e38f; thr[i] = -1.f; }

    // staging: linear LDS dest, source pre-swizzled (16B chunk XOR row&7). tile = 128 codes.
#define STAGE(BUF, KT) do { \
    const u16* wsrc_ = wb + (size_t)(KT) * (128 * 128); \
    _Pragma("unroll") \
    for (int q_ = 0; q_ < 4; ++q_) { \
        int r_ = w * 16 + q_ * 4 + (lane >> 4); \
        int c_ = (lane & 15) ^ (r_ & 7); \
        GLOAD16(wsrc_ + r_ * 128 + c_ * 8, &Wb[BUF][(w * 16 + q_ * 4) * 128]); \
    } \
} while (0)

    // compute one 128-code tile: 16 MFMA, distances, running min, candidate collect
#define COMPUTE(BUF, KT, COLLECT) do { \
    f32x4 acc[2][2] = {}; \
    _Pragma("unroll") \
    for (int ks_ = 0; ks_ < 4; ++ks_) { \
        int cl0_ = wc * 32 + (lane & 15); \
        int sb0_ = (ks_ * 4 + (lane >> 4)) ^ (cl0_ & 7); \
        short8 bv0_ = *(const short8*)&Wb[BUF][cl0_ * 128 + sb0_ * 8]; \
        int cl1_ = cl0_ + 16; \
        int sb1_ = (ks_ * 4 + (lane >> 4)) ^ (cl1_ & 7); \
        short8 bv1_ = *(const short8*)&Wb[BUF][cl1_ * 128 + sb1_ * 8]; \
        acc[0][0] = __builtin_amdgcn_mfma_f32_16x16x32_bf16(af[0][ks_], bv0_, acc[0][0], 0, 0, 0); \
        acc[0][1] = __builtin_amdgcn_mfma_f32_16x16x32_bf16(af[0][ks_], bv1_, acc[0][1], 0, 0, 0); \
        acc[1][0] = __builtin_amdgcn_mfma_f32_16x16x32_bf16(af[1][ks_], bv0_, acc[1][0], 0, 0, 0); \
        acc[1][1] = __builtin_amdgcn_mfma_f32_16x16x32_bf16(af[1][ks_], bv1_, acc[1][1], 0, 0, 0); \
    } \
    float dd[2][2][4]; \
    float hm_ = 1.0f; \
    _Pragma("unroll") \
    for (int mi_ = 0; mi_ < 2; ++mi_) \
        _Pragma("unroll") \
        for (int e_ = 0; e_ < 4; ++e_) { \
            float d0_ = fmaf(acc[mi_][0][e_], -2.f, 2.125f); \
            float d1_ = fmaf(acc[mi_][1][e_], -2.f, 2.125f); \
            dd[mi_][0][e_] = d0_; dd[mi_][1][e_] = d1_; \
            int i_ = mi_ * 4 + e_; \
            bmin[i_] = fminf(bmin[i_], fminf(d0_, d1_)); \
            hm_ = fminf(hm_, fminf(d0_, d1_) - thr[i_]); \
        } \
    if (COLLECT && hm_ <= 0.0f) { \
        _Pragma("unroll") \
        for (int mi_ = 0; mi_ < 2; ++mi_) \
            _Pragma("unroll") \
            for (int ni_ = 0; ni_ < 2; ++ni_) \
                _Pragma("unroll") \
                for (int e_ = 0; e_ < 4; ++e_) { \
                    if (dd[mi_][ni_][e_] <= thr[mi_ * 4 + e_]) { \
                        u32 rl_ = (u32)(wr * 32 + mi_ * 16 + (lane >> 4) * 4 + e_); \
                        u32 cd_ = (u32)((KT) * 128 + wc * 32 + ni_ * 16 + (lane & 15)); \
                        int qi_ = atomicAdd(&qcnt, 1); \
                        if (qi_ < QCAP) queue[qi_] = (rl_ << 13) | cd_; \
                    } \
                } \
    } \
} while (0)

#define REFRESH() do { \
    _Pragma("unroll") \
    for (int i_ = 0; i_ < 8; ++i_) { \
        float v_ = bmin[i_]; \
        v_ = fminf(v_, __shfl_xor(v_, 1, 64)); \
        v_ = fminf(v_, __shfl_xor(v_, 2, 64)); \
        v_ = fminf(v_, __shfl_xor(v_, 4, 64)); \
        v_ = fminf(v_, __shfl_xor(v_, 8, 64)); \
        if ((lane & 15) == 0) \
            atomicMin(&rowMinU[wr * 32 + (i_ >> 2) * 16 + (lane >> 4) * 4 + (i_ & 3)], __float_as_uint(v_)); \
    } \
    _Pragma("unroll") \
    for (int i_ = 0; i_ < 8; ++i_) \
        thr[i_] = fminf(__uint_as_float(rowMinU[wr * 32 + (i_ >> 2) * 16 + (lane >> 4) * 4 + (i_ & 3)]), bmin[i_]) + MARGIN; \
} while (0)

    // ---- prologue: seed thresholds from tiles 0-1 (no collection) ----
    STAGE(0, 0);
    __syncthreads();
    COMPUTE(0, 0, false);
    STAGE(1, 1);
    __syncthreads();
    COMPUTE(1, 1, false);
    REFRESH();
    // invariant: buf0 = tile0, buf1 = tile1, both drained

    // ---- main sweep: 64 tiles, 1 barrier per tile, prefetch covered by compute ----
    #pragma unroll 1
    for (int kt = 0; kt < 64; ++kt) {
        const int bfi = kt & 1;
        COMPUTE(bfi, kt, true);
        if ((kt & 1) == 1) REFRESH();
        __syncthreads();                    // drains own gload_lds (tile kt+1) + barrier
        STAGE(bfi, (kt + 2) & 63);          // fire-and-forget next-next tile
    }
    __syncthreads();

    // ---- exact fp32 repair: one candidate per 16-lane group (32 groups) ----
    {
        int nq = qcnt < QCAP ? qcnt : QCAP;
        int gq = t >> 4, l = t & 15;
        for (int qi = gq; qi < nq; qi += 32) {
            u32 e = queue[qi];
            int rl = e >> 13;
            int code = e & 0x1FFF;
            const float4* zr = (const float4*)&ztl[rl * ZSTR + l * 8];
            const float4* wr2 = (const float4*)(wgt + (size_t)code * DCH + l * 8);
            float4 za = zr[0], zb = zr[1], wa = wr2[0], wbv = wr2[1];
            float s = 0.f;
            s = fmaf(za.x, wa.x, s); s = fmaf(za.y, wa.y, s);
            s = fmaf(za.z, wa.z, s); s = fmaf(za.w, wa.w, s);
            s = fmaf(zb.x, wbv.x, s); s = fmaf(zb.y, wbv.y, s);
            s = fmaf(zb.z, wbv.z, s); s = fmaf(zb.w, wbv.w, s);
            s += __shfl_xor(s, 1, 64);
            s += __shfl_xor(s, 2, 64);
            s += __shfl_xor(s, 4, 64);
            s += __shfl_xor(s, 8, 64);
            if (l == 0) {
                float ed = csq[code] - 2.0f * s;
                u64 key = ((u64)mono(ed) << 32) | (u32)code;
                atomicMin((unsigned long long*)&finalkey[rl], (unsigned long long)key);
            }
        }
    }
    __syncthreads();

    // ---- finalize: indices, direct gather, straight-through output, loss ----
    if (t < ROWS) {
        u32 code = (u32)finalkey[t];
        codes[t] = (int)code;
        out[ZQ_SZ + 1 + n0 + t] = (float)code;
    }
    __syncthreads();
    {
        const float4* wrp = (const float4*)(wgt + (size_t)codes[p] * DCH + w * 16);
        float4 wv0 = wrp[0], wv1 = wrp[1], wv2 = wrp[2], wv3 = wrp[3];
        float wvf[16] = { wv0.x, wv0.y, wv0.z, wv0.w, wv1.x, wv1.y, wv1.z, wv1.w,
                          wv2.x, wv2.y, wv2.z, wv2.w, wv3.x, wv3.y, wv3.z, wv3.w };
        float* ob = out + (size_t)b * DCH * HW + hw0;
        float sq = 0.f;
        #pragma unroll
        for (int j = 0; j < 16; ++j) {
            int c = w * 16 + j;
            float zv = ztl[p * ZSTR + c];
            float diff = wvf[j] - zv;
            ob[(size_t)c * HW + p] = zv + diff;   // straight-through forward value
            sq += diff * diff;
        }
        #pragma unroll
        for (int o = 32; o > 0; o >>= 1) sq += __shfl_down(sq, o, 64);
        if (lane == 0) lsum[w] = sq;
    }
    __syncthreads();
    if (t == 0) {
        float s = lsum[0] + lsum[1] + lsum[2] + lsum[3]
                + lsum[4] + lsum[5] + lsum[6] + lsum[7];
        atomicAdd(out + ZQ_SZ, s * (BETA / (float)ZQ_SZ));
    }

#undef STAGE
#undef COMPUTE
#undef REFRESH
}

extern "C" void kernel_launch(void* const* d_in, const int* in_sizes, int n_in,
                              void* d_out, int out_size, void* d_ws, size_t ws_size,
                              hipStream_t stream) {
    const float* z = (const float*)d_in[0];
    const float* w = (const float*)d_in[1];
    float* out = (float*)d_out;
    float* wsf = (float*)d_ws;

    // ws layout: wb u16[1048576] (= 524288 floats) | csq f32[8192]
    u16* wb = (u16*)wsf;
    float* csq = wsf + 524288;

    kwprep<<<512, 256, 0, stream>>>(w, wb, csq);
    hipMemsetAsync(out + ZQ_SZ, 0, 4, stream);      // zero the loss slot
    kmain<<<256, 512, 0, stream>>>(z, w, wb, csq, out);
}

// Round 7
// 164.304 us; speedup vs baseline: 1.3001x; 1.2946x over previous
//
#include <hip/hip_runtime.h>
#include <hip/hip_bf16.h>

typedef unsigned int u32;
typedef unsigned long long u64;
typedef unsigned short u16;

#define NPOS 16384      // B*H*W
#define DCH  128
#define KCB  8192
#define HW   1024
#define BETA 0.25f
#define ZQ_SZ 2097152
#define MARGIN 0.022f   // >= 2*delta_bf16 (0.0157) + headroom
#define QCAP 4096
#define ZSTR 132        // ztl LDS row stride in floats
#define ROWS 64         // rows per block

typedef __attribute__((ext_vector_type(8))) short short8;
typedef __attribute__((ext_vector_type(4))) float f32x4;

#define GLOAD16(G, L) __builtin_amdgcn_global_load_lds( \
    (const __attribute__((address_space(1))) u32*)(const void*)(G), \
    (__attribute__((address_space(3))) u32*)(void*)(L), 16, 0, 0)

__device__ inline u16 f2bf(float x) {   // RNE float->bf16
    u32 u = __float_as_uint(x);
    return (u16)((u + 0x7FFFu + ((u >> 16) & 1u)) >> 16);
}
__device__ inline u32 mono(float f) {   // monotone float->u32
    u32 b = __float_as_uint(f);
    return (b & 0x80000000u) ? ~b : (b | 0x80000000u);
}

// ---------------- codebook prep: bf16 convert + squared norms ----------------
__global__ __launch_bounds__(256) void kwprep(const float* __restrict__ w,
                                              u16* __restrict__ wb,
                                              float* __restrict__ csq) {
    const int t = threadIdx.x;
    const int row = blockIdx.x * 16 + (t >> 4);
    const int l = t & 15;
    const float4* src = (const float4*)(w + (size_t)row * DCH + l * 8);
    float4 a = src[0], b = src[1];
    float s = a.x*a.x + a.y*a.y + a.z*a.z + a.w*a.w
            + b.x*b.x + b.y*b.y + b.z*b.z + b.w*b.w;
    union { u16 h[8]; uint4 v; } u;
    u.h[0]=f2bf(a.x); u.h[1]=f2bf(a.y); u.h[2]=f2bf(a.z); u.h[3]=f2bf(a.w);
    u.h[4]=f2bf(b.x); u.h[5]=f2bf(b.y); u.h[6]=f2bf(b.z); u.h[7]=f2bf(b.w);
    *(uint4*)(wb + (size_t)row * DCH + l * 8) = u.v;
    s += __shfl_xor(s, 1, 64);
    s += __shfl_xor(s, 2, 64);
    s += __shfl_xor(s, 4, 64);
    s += __shfl_xor(s, 8, 64);
    if (l == 0) csq[row] = s;
}

// ---- fused main: wave-private staging, zero-barrier counted-vmcnt sweep ----
__global__ __launch_bounds__(512, 2) void kmain(const float* __restrict__ z,
                                                const float* __restrict__ wgt,
                                                const u16* __restrict__ wb,
                                                const float* __restrict__ csq,
                                                float* __restrict__ out) {
    __shared__ __align__(16) u16 Wpriv[8][3][16 * 128];  // 96 KB: 8 waves x 3 bufs x 4KB
    __shared__ __align__(16) float ztl[ROWS * ZSTR];     // 33.8 KB fp32 normalized rows
    __shared__ u32 queue[QCAP];                          // 16 KB candidate queue
    __shared__ u32 rowMinU[ROWS];
    __shared__ u64 finalkey[ROWS];
    __shared__ float psum[ROWS][8];
    __shared__ float invL[ROWS];
    __shared__ int codes[ROWS];
    __shared__ float lsum[8];
    __shared__ int qcnt;

    const int t = threadIdx.x;                 // 0..511
    const int lane = t & 63;
    const int w = t >> 6;                      // wave 0..7: owns codes w*16.. per tile
    const int lr = lane & 15, lk = lane >> 4;
    const int n0 = blockIdx.x * ROWS;
    const int b = n0 >> 10, hw0 = n0 & 1023;
    const int p = lane;

    // ---- phase 0: load + l2-normalize 64 rows into LDS ----
    float vch[16];
    {
        const float* zp = z + (size_t)b * DCH * HW + hw0 + p;
        #pragma unroll
        for (int j = 0; j < 16; ++j)
            vch[j] = zp[(size_t)(w * 16 + j) * HW];
        float s = 0.f;
        #pragma unroll
        for (int j = 0; j < 16; ++j) s += vch[j] * vch[j];
        psum[p][w] = s;
    }
    if (t < ROWS) { rowMinU[t] = 0x7f800000u; finalkey[t] = ~0ULL; }
    if (t == 0) qcnt = 0;
    __syncthreads();
    if (t < ROWS) {
        float ss = 0.f;
        #pragma unroll
        for (int j = 0; j < 8; ++j) ss += psum[t][j];
        invL[t] = 1.0f / fmaxf(sqrtf(ss), 1e-12f);
    }
    __syncthreads();
    {
        float inv = invL[p];
        #pragma unroll
        for (int j = 0; j < 16; ++j)
            ztl[p * ZSTR + w * 16 + j] = vch[j] * inv;
    }
    __syncthreads();

    // ---- A fragments (bf16): all 64 rows per wave. row = lane&15, k=(lane>>4)*8+j ----
    short8 af[4][4];
    #pragma unroll
    for (int rt = 0; rt < 4; ++rt)
        #pragma unroll
        for (int ks = 0; ks < 4; ++ks) {
            int row = rt * 16 + lr;
            int kb = ks * 32 + lk * 8;
            const float4* zr = (const float4*)&ztl[row * ZSTR + kb];
            float4 x0 = zr[0], x1 = zr[1];
            union { u16 h[8]; short8 v; } uu;
            uu.h[0]=f2bf(x0.x); uu.h[1]=f2bf(x0.y); uu.h[2]=f2bf(x0.z); uu.h[3]=f2bf(x0.w);
            uu.h[4]=f2bf(x1.x); uu.h[5]=f2bf(x1.y); uu.h[6]=f2bf(x1.z); uu.h[7]=f2bf(x1.w);
            af[rt][ks] = uu.v;
        }

    u16* mybuf = &Wpriv[w][0][0];   // 3 consecutive 2048-u16 buffers

    // stage tile KT's 16 own codes (4 KB dense) into buffer BUFO (element offset)
#define STAGE(BUFO, KT) do { \
    const u16* src_ = wb + (size_t)(KT) * 16384 + w * 16 * 128; \
    _Pragma("unroll") \
    for (int q_ = 0; q_ < 4; ++q_) { \
        int rloc_ = q_ * 4 + lk; \
        int c_ = lr ^ (rloc_ & 7); \
        GLOAD16(src_ + rloc_ * 128 + c_ * 8, mybuf + (BUFO) + q_ * 512); \
    } \
} while (0)

    // read B frags + 16 MFMA + epilogue for tile KT from buffer BUFO
#define COMPUTE(BUFO, KT, COLLECT) do { \
    short8 bf_[4]; \
    _Pragma("unroll") \
    for (int ks_ = 0; ks_ < 4; ++ks_) { \
        int slot_ = (ks_ * 4 + lk) ^ (lr & 7); \
        bf_[ks_] = *(const short8*)(mybuf + (BUFO) + lr * 128 + slot_ * 8); \
    } \
    __builtin_amdgcn_s_waitcnt(0 /*lgkmcnt(0) vmcnt(0)*/ ); \
    STAGE_NEXT; \
    f32x4 acc_[4] = {}; \
    _Pragma("unroll") \
    for (int ks_ = 0; ks_ < 4; ++ks_) { \
        acc_[0] = __builtin_amdgcn_mfma_f32_16x16x32_bf16(af[0][ks_], bf_[ks_], acc_[0], 0, 0, 0); \
        acc_[1] = __builtin_amdgcn_mfma_f32_16x16x32_bf16(af[1][ks_], bf_[ks_], acc_[1], 0, 0, 0); \
        acc_[2] = __builtin_amdgcn_mfma_f32_16x16x32_bf16(af[2][ks_], bf_[ks_], acc_[2], 0, 0, 0); \
        acc_[3] = __builtin_amdgcn_mfma_f32_16x16x32_bf16(af[3][ks_], bf_[ks_], acc_[3], 0, 0, 0); \
    } \
    float hm_ = 1.0f; \
    float dv_[16]; \
    _Pragma("unroll") \
    for (int rt_ = 0; rt_ < 4; ++rt_) \
        _Pragma("unroll") \
        for (int e_ = 0; e_ < 4; ++e_) { \
            int i_ = rt_ * 4 + e_; \
            float d_ = fmaf(acc_[rt_][e_], -2.f, 2.125f); \
            dv_[i_] = d_; \
            bmin[i_] = fminf(bmin[i_], d_); \
            hm_ = fminf(hm_, d_ - thr[i_]); \
        } \
    if (COLLECT && hm_ <= 0.0f) { \
        u32 cd_ = (u32)((KT) * 128 + w * 16 + lr); \
        _Pragma("unroll") \
        for (int rt_ = 0; rt_ < 4; ++rt_) \
            _Pragma("unroll") \
            for (int e_ = 0; e_ < 4; ++e_) { \
                if (dv_[rt_ * 4 + e_] <= thr[rt_ * 4 + e_]) { \
                    u32 rl_ = (u32)(rt_ * 16 + lk * 4 + e_); \
                    int qi_ = atomicAdd(&qcnt, 1); \
                    if (qi_ < QCAP) queue[qi_] = (rl_ << 13) | cd_; \
                } \
            } \
    } \
} while (0)

#define REFRESH() do { \
    _Pragma("unroll") \
    for (int i_ = 0; i_ < 16; ++i_) { \
        float v_ = bmin[i_]; \
        v_ = fminf(v_, __shfl_xor(v_, 1, 64)); \
        v_ = fminf(v_, __shfl_xor(v_, 2, 64)); \
        v_ = fminf(v_, __shfl_xor(v_, 4, 64)); \
        v_ = fminf(v_, __shfl_xor(v_, 8, 64)); \
        if (lr == 0) \
            atomicMin(&rowMinU[(i_ >> 2) * 16 + lk * 4 + (i_ & 3)], __float_as_uint(v_)); \
    } \
    _Pragma("unroll") \
    for (int i_ = 0; i_ < 16; ++i_) \
        thr[i_] = fminf(__uint_as_float(rowMinU[(i_ >> 2) * 16 + lk * 4 + (i_ & 3)]), bmin[i_]) + MARGIN; \
} while (0)

    float bmin[16], thr[16];
    #pragma unroll
    for (int i = 0; i < 16; ++i) { bmin[i] = 3.4e38f; thr[i] = -1.f; }

    // ---- prologue: fill depth-3 pipeline, seed thresholds from tiles 0-1 ----
    STAGE(0, 0);
    STAGE(2048, 1);
    STAGE(4096, 2);
    asm volatile("s_waitcnt vmcnt(8)" ::: "memory");
    __builtin_amdgcn_sched_barrier(0);
#define STAGE_NEXT do {} while (0)
    {
        COMPUTE(0, 0, false);       // seeds bmin from tile 0 (no restage inside)
    }
    asm volatile("s_waitcnt vmcnt(4)" ::: "memory");
    __builtin_amdgcn_sched_barrier(0);
    {
        COMPUTE(2048, 1, false);
    }
#undef STAGE_NEXT
    REFRESH();

    // ---- main sweep: 64 tiles, zero barriers, counted vmcnt (never 0) ----
    int bufo = 0;
    #pragma unroll 1
    for (int kt = 0; kt < 64; ++kt) {
        asm volatile("s_waitcnt vmcnt(8)" ::: "memory");
        __builtin_amdgcn_sched_barrier(0);
#define STAGE_NEXT STAGE(bufo, (kt + 3) & 63)
        COMPUTE(bufo, kt, true);
#undef STAGE_NEXT
        if ((kt & 7) == 7) REFRESH();
        bufo += 2048;
        if (bufo == 6144) bufo = 0;
    }

    __syncthreads();   // single barrier: all candidates in queue, all LDS settled

    // ---- exact fp32 repair: one candidate per 16-lane group (32 groups) ----
    {
        int nq = qcnt < QCAP ? qcnt : QCAP;
        int gq = t >> 4, l = t & 15;
        for (int qi = gq; qi < nq; qi += 32) {
            u32 e = queue[qi];
            int rl = e >> 13;
            int code = e & 0x1FFF;
            const float4* zr = (const float4*)&ztl[rl * ZSTR + l * 8];
            const float4* wr2 = (const float4*)(wgt + (size_t)code * DCH + l * 8);
            float4 za = zr[0], zb = zr[1], wa = wr2[0], wbv = wr2[1];
            float s = 0.f;
            s = fmaf(za.x, wa.x, s); s = fmaf(za.y, wa.y, s);
            s = fmaf(za.z, wa.z, s); s = fmaf(za.w, wa.w, s);
            s = fmaf(zb.x, wbv.x, s); s = fmaf(zb.y, wbv.y, s);
            s = fmaf(zb.z, wbv.z, s); s = fmaf(zb.w, wbv.w, s);
            s += __shfl_xor(s, 1, 64);
            s += __shfl_xor(s, 2, 64);
            s += __shfl_xor(s, 4, 64);
            s += __shfl_xor(s, 8, 64);
            if (l == 0) {
                float ed = csq[code] - 2.0f * s;
                u64 key = ((u64)mono(ed) << 32) | (u32)code;
                atomicMin((unsigned long long*)&finalkey[rl], (unsigned long long)key);
            }
        }
    }
    __syncthreads();

    // ---- finalize: indices, direct gather, straight-through output, loss ----
    if (t < ROWS) {
        u32 code = (u32)finalkey[t];
        codes[t] = (int)code;
        out[ZQ_SZ + 1 + n0 + t] = (float)code;
    }
    __syncthreads();
    {
        const float4* wrp = (const float4*)(wgt + (size_t)codes[p] * DCH + w * 16);
        float4 wv0 = wrp[0], wv1 = wrp[1], wv2 = wrp[2], wv3 = wrp[3];
        float wvf[16] = { wv0.x, wv0.y, wv0.z, wv0.w, wv1.x, wv1.y, wv1.z, wv1.w,
                          wv2.x, wv2.y, wv2.z, wv2.w, wv3.x, wv3.y, wv3.z, wv3.w };
        float* ob = out + (size_t)b * DCH * HW + hw0;
        float sq = 0.f;
        #pragma unroll
        for (int j = 0; j < 16; ++j) {
            int c = w * 16 + j;
            float zv = ztl[p * ZSTR + c];
            float diff = wvf[j] - zv;
            ob[(size_t)c * HW + p] = zv + diff;   // straight-through forward value
            sq += diff * diff;
        }
        #pragma unroll
        for (int o = 32; o > 0; o >>= 1) sq += __shfl_down(sq, o, 64);
        if (lane == 0) lsum[w] = sq;
    }
    __syncthreads();
    if (t == 0) {
        float s = lsum[0] + lsum[1] + lsum[2] + lsum[3]
                + lsum[4] + lsum[5] + lsum[6] + lsum[7];
        atomicAdd(out + ZQ_SZ, s * (BETA / (float)ZQ_SZ));
    }

#undef STAGE
#undef COMPUTE
#undef REFRESH
}

extern "C" void kernel_launch(void* const* d_in, const int* in_sizes, int n_in,
                              void* d_out, int out_size, void* d_ws, size_t ws_size,
                              hipStream_t stream) {
    const float* z = (const float*)d_in[0];
    const float* w = (const float*)d_in[1];
    float* out = (float*)d_out;
    float* wsf = (float*)d_ws;

    // ws layout: wb u16[1048576] (= 524288 floats) | csq f32[8192]
    u16* wb = (u16*)wsf;
    float* csq = wsf + 524288;

    kwprep<<<512, 256, 0, stream>>>(w, wb, csq);
    hipMemsetAsync(out + ZQ_SZ, 0, 4, stream);      // zero the loss slot
    kmain<<<256, 512, 0, stream>>>(z, w, wb, csq, out);
}